// Round 1
// baseline (654.550 us; speedup 1.0000x reference)
//
#include <hip/hip_runtime.h>
#include <math.h>

typedef __bf16 bf16_t;
typedef __bf16 bf16x8 __attribute__((ext_vector_type(8)));
typedef __bf16 bf16x4 __attribute__((ext_vector_type(4)));
typedef float  f32x4  __attribute__((ext_vector_type(4)));

#define DEV __device__ __forceinline__

DEV void gl_lds16(const bf16_t* g, bf16_t* l) {
  __builtin_amdgcn_global_load_lds(
      (const __attribute__((address_space(1))) void*)g,
      (__attribute__((address_space(3))) void*)l, 16, 0, 0);
}

// ---------------- cast f32 -> bf16 (vectorized) ----------------
__global__ void k_cast_bf16(const float* __restrict__ src, bf16_t* __restrict__ dst, int n4) {
  int idx = blockIdx.x * blockDim.x + threadIdx.x;
  int stride = gridDim.x * blockDim.x;
  const float4* s4 = (const float4*)src;
  for (int i = idx; i < n4; i += stride) {
    float4 v = s4[i];
    bf16x4 o;
    o[0] = (bf16_t)v.x; o[1] = (bf16_t)v.y; o[2] = (bf16_t)v.z; o[3] = (bf16_t)v.w;
    *(bf16x4*)(dst + (size_t)i * 4) = o;
  }
}

// ---------------- transpose + cast weight [1024][1024] f32 -> [N][K] bf16 ----------------
__global__ __launch_bounds__(256) void k_transpose_cast(const float* __restrict__ W, bf16_t* __restrict__ Wt) {
  __shared__ float tile[64][65];
  int k0 = blockIdx.x * 64, n0 = blockIdx.y * 64;
  int r = threadIdx.x >> 2;
  int c0 = (threadIdx.x & 3) * 16;
  const float4* src = (const float4*)(W + (size_t)(k0 + r) * 1024 + n0 + c0);
#pragma unroll
  for (int i = 0; i < 4; ++i) {
    float4 v = src[i];
    tile[r][c0 + i * 4 + 0] = v.x;
    tile[r][c0 + i * 4 + 1] = v.y;
    tile[r][c0 + i * 4 + 2] = v.z;
    tile[r][c0 + i * 4 + 3] = v.w;
  }
  __syncthreads();
#pragma unroll
  for (int half = 0; half < 2; ++half) {
    bf16x8 o;
#pragma unroll
    for (int j = 0; j < 8; ++j) o[j] = (bf16_t)tile[c0 + half * 8 + j][r];
    *(bf16x8*)(Wt + (size_t)(n0 + r) * 1024 + k0 + c0 + half * 8) = o;
  }
}

// ---------------- reversed sinusoidal table [2048][1024] bf16 ----------------
__global__ void k_sinusoid(bf16_t* __restrict__ tab) {
  int i = blockIdx.x;   // row
  int d = threadIdx.x;  // 0..511
  float pos = (float)(2047 - i);
  const float coef = (float)(-9.210340371976184 / 511.0);  // -ln(10000)/(n-1)
  float inv = expf((float)d * coef);
  float st = pos * inv;
  tab[(size_t)i * 1024 + d]       = (bf16_t)sinf(st);
  tab[(size_t)i * 1024 + 512 + d] = (bf16_t)cosf(st);
}

// ---------------- GEMM: C[M][1024] = A[M][1024] @ Bt[1024][1024]^T(+bias) ----------------
// A row-major [M][K], Bt row-major [N][K] (i.e. W transposed). 128x128 tile, BK=64.
__global__ __launch_bounds__(256) void k_gemm(
    const bf16_t* __restrict__ A, const bf16_t* __restrict__ Bt,
    const float* __restrict__ bias,
    const float* __restrict__ eb1, bf16_t* __restrict__ out1,
    const float* __restrict__ eb2, bf16_t* __restrict__ out2,
    float* __restrict__ outF) {
  __shared__ bf16_t As[128 * 64];
  __shared__ bf16_t Bs[128 * 64];
  const int m0 = blockIdx.x * 128, n0 = blockIdx.y * 128;
  const int tid = threadIdx.x;
  const int w = tid >> 6, lane = tid & 63, li = lane & 15, g = lane >> 4;
  const int mb = (w >> 1) * 64, nb = (w & 1) * 64;
  f32x4 acc[4][4] = {};
  for (int kt = 0; kt < 16; ++kt) {
    __syncthreads();
#pragma unroll
    for (int it = 0; it < 4; ++it) {
      int chunk = it * 256 + tid;
      int r = chunk >> 3, kg = chunk & 7;
      gl_lds16(A + (size_t)(m0 + r) * 1024 + kt * 64 + kg * 8, &As[chunk * 8]);
      gl_lds16(Bt + (size_t)(n0 + r) * 1024 + kt * 64 + kg * 8, &Bs[chunk * 8]);
    }
    __syncthreads();
#pragma unroll
    for (int kk = 0; kk < 64; kk += 32) {
      bf16x8 a[4], b[4];
#pragma unroll
      for (int x = 0; x < 4; ++x) {
        a[x] = *(const bf16x8*)&As[(mb + x * 16 + li) * 64 + kk + g * 8];
        b[x] = *(const bf16x8*)&Bs[(nb + x * 16 + li) * 64 + kk + g * 8];
      }
#pragma unroll
      for (int mr = 0; mr < 4; ++mr)
#pragma unroll
        for (int nr = 0; nr < 4; ++nr)
          acc[mr][nr] = __builtin_amdgcn_mfma_f32_16x16x32_bf16(a[mr], b[nr], acc[mr][nr], 0, 0, 0);
    }
  }
#pragma unroll
  for (int mr = 0; mr < 4; ++mr)
#pragma unroll
    for (int nr = 0; nr < 4; ++nr)
#pragma unroll
      for (int r4 = 0; r4 < 4; ++r4) {
        int row = m0 + mb + mr * 16 + g * 4 + r4;
        int col = n0 + nb + nr * 16 + li;
        float v = acc[mr][nr][r4] + (bias ? bias[col] : 0.f);
        size_t off = (size_t)row * 1024 + col;
        if (out1) out1[off] = (bf16_t)(v + (eb1 ? eb1[col] : 0.f));
        if (out2) out2[off] = (bf16_t)(v + (eb2 ? eb2[col] : 0.f));
        if (outF) outF[off] = v;
      }
}

// ---------------- fused rel-attention ----------------
// grid (32 tblocks, 16 heads, 2 batch), 256 threads (4 waves), 64 q-rows / WG.
__global__ __launch_bounds__(256) void k_attn(
    const bf16_t* __restrict__ qw, const bf16_t* __restrict__ qr,
    const bf16_t* __restrict__ kb, const bf16_t* __restrict__ vb,
    const bf16_t* __restrict__ peb, const float* __restrict__ mask,
    bf16_t* __restrict__ attnb) {
  const int t0 = blockIdx.x * 64;
  const int h = blockIdx.y;
  const int b = blockIdx.z;
  const int tid = threadIdx.x;
  const int w = tid >> 6, lane = tid & 63, li = lane & 15, g = lane >> 4;

  __shared__ bf16_t qw_s[64 * 72];
  __shared__ bf16_t qr_s[65 * 72];
  __shared__ bf16_t k_s[64 * 72];
  __shared__ bf16_t vt_s[64 * 72];
  __shared__ bf16_t pe_s[128 * 72];
  __shared__ float  R_s[64 * 132];
  __shared__ bf16_t p_s[64 * 72];

  const size_t base_bh = (size_t)b * 2048 * 1024 + (size_t)h * 64;

  {  // stage qw rows t0..t0+63, qr rows t0..t0+64 (row 64 clamped to 0)
    int row = tid >> 2, d0 = (tid & 3) * 16;
    const bf16_t* s1 = qw + base_bh + (size_t)(t0 + row) * 1024 + d0;
    *(bf16x8*)&qw_s[row * 72 + d0]     = *(const bf16x8*)s1;
    *(bf16x8*)&qw_s[row * 72 + d0 + 8] = *(const bf16x8*)(s1 + 8);
    const bf16_t* s2 = qr + base_bh + (size_t)(t0 + row) * 1024 + d0;
    *(bf16x8*)&qr_s[row * 72 + d0]     = *(const bf16x8*)s2;
    *(bf16x8*)&qr_s[row * 72 + d0 + 8] = *(const bf16x8*)(s2 + 8);
    if (tid < 4) {
      int dd = tid * 16;
      if (t0 + 64 < 2048) {
        const bf16_t* s3 = qr + base_bh + (size_t)(t0 + 64) * 1024 + dd;
        *(bf16x8*)&qr_s[64 * 72 + dd]     = *(const bf16x8*)s3;
        *(bf16x8*)&qr_s[64 * 72 + dd + 8] = *(const bf16x8*)(s3 + 8);
      } else {
        for (int j = 0; j < 16; ++j) qr_s[64 * 72 + dd + j] = (bf16_t)0.f;
      }
    }
  }

  float mrun[4], lrun[4];
  f32x4 oacc[4] = {};
#pragma unroll
  for (int r4 = 0; r4 < 4; ++r4) { mrun[r4] = -1e30f; lrun[r4] = 0.f; }

  for (int j0 = 0; j0 < 2048; j0 += 64) {
    __syncthreads();
    {  // stage K tile and V^T tile
      int row = tid >> 2, d0 = (tid & 3) * 16;
      const bf16_t* sk = kb + base_bh + (size_t)(j0 + row) * 1024 + d0;
      *(bf16x8*)&k_s[row * 72 + d0]     = *(const bf16x8*)sk;
      *(bf16x8*)&k_s[row * 72 + d0 + 8] = *(const bf16x8*)(sk + 8);
      const bf16_t* sv = vb + base_bh + (size_t)(j0 + row) * 1024 + d0;
      bf16x8 v0 = *(const bf16x8*)sv;
      bf16x8 v1 = *(const bf16x8*)(sv + 8);
#pragma unroll
      for (int j = 0; j < 8; ++j) {
        vt_s[(d0 + j) * 72 + row]     = v0[j];
        vt_s[(d0 + 8 + j) * 72 + row] = v1[j];
      }
    }
    __syncthreads();

    // content scores: S[i, jj] = qw_{t0+i} . k_{j0+jj}
    f32x4 sc[4] = {};
#pragma unroll
    for (int kk = 0; kk < 64; kk += 32) {
      bf16x8 aq = *(const bf16x8*)&qw_s[(w * 16 + li) * 72 + kk + g * 8];
#pragma unroll
      for (int ct = 0; ct < 4; ++ct) {
        bf16x8 bk = *(const bf16x8*)&k_s[(ct * 16 + li) * 72 + kk + g * 8];
        sc[ct] = __builtin_amdgcn_mfma_f32_16x16x32_bf16(aq, bk, sc[ct], 0, 0, 0);
      }
    }

    float srel[4][4] = {};
    const bool needA = (j0 <= t0), needB = (j0 >= t0);

    if (needA) {  // rel case A: d=j-t<=0, R[i,cc]=qr_{t0+i}.pe[cA0+cc]
      const int cA0 = 1984 + j0 - t0;
      __syncthreads();
      {
        int cc = tid >> 1, d0 = (tid & 1) * 32;
        int c = cA0 + cc;
        if (c >= 0 && c < 2048) {
          const bf16_t* sp = peb + (size_t)c * 1024 + h * 64 + d0;
#pragma unroll
          for (int q = 0; q < 4; ++q)
            *(bf16x8*)&pe_s[cc * 72 + d0 + q * 8] = *(const bf16x8*)(sp + q * 8);
        } else {
          for (int j = 0; j < 32; ++j) pe_s[cc * 72 + d0 + j] = (bf16_t)0.f;
        }
      }
      __syncthreads();
      f32x4 ra[8] = {};
#pragma unroll
      for (int kk = 0; kk < 64; kk += 32) {
        bf16x8 aq = *(const bf16x8*)&qr_s[(w * 16 + li) * 72 + kk + g * 8];
#pragma unroll
        for (int ct = 0; ct < 8; ++ct) {
          bf16x8 bp = *(const bf16x8*)&pe_s[(ct * 16 + li) * 72 + kk + g * 8];
          ra[ct] = __builtin_amdgcn_mfma_f32_16x16x32_bf16(aq, bp, ra[ct], 0, 0, 0);
        }
      }
#pragma unroll
      for (int ct = 0; ct < 8; ++ct)
#pragma unroll
        for (int r4 = 0; r4 < 4; ++r4)
          R_s[(w * 16 + g * 4 + r4) * 132 + ct * 16 + li] = ra[ct][r4];
      __syncthreads();
#pragma unroll
      for (int ct = 0; ct < 4; ++ct)
#pragma unroll
        for (int r4 = 0; r4 < 4; ++r4) {
          int i = w * 16 + g * 4 + r4;
          int jj = ct * 16 + li;
          int sd = (j0 + jj) - (t0 + i);
          if (sd <= 0) srel[ct][r4] = R_s[i * 132 + (jj - i + 63)];
        }
    }

    if (needB) {  // rel case B: d>=2 uses NEXT q row: R[i,cc]=qr_{t0+1+i}.pe[cB0+cc]
      const int cB0 = j0 - t0 - 65;
      __syncthreads();
      {
        int cc = tid >> 1, d0 = (tid & 1) * 32;
        int c = cB0 + cc;
        if (c >= 0 && c < 2048) {
          const bf16_t* sp = peb + (size_t)c * 1024 + h * 64 + d0;
#pragma unroll
          for (int q = 0; q < 4; ++q)
            *(bf16x8*)&pe_s[cc * 72 + d0 + q * 8] = *(const bf16x8*)(sp + q * 8);
        } else {
          for (int j = 0; j < 32; ++j) pe_s[cc * 72 + d0 + j] = (bf16_t)0.f;
        }
      }
      __syncthreads();
      f32x4 ra[8] = {};
#pragma unroll
      for (int kk = 0; kk < 64; kk += 32) {
        bf16x8 aq = *(const bf16x8*)&qr_s[(w * 16 + li + 1) * 72 + kk + g * 8];
#pragma unroll
        for (int ct = 0; ct < 8; ++ct) {
          bf16x8 bp = *(const bf16x8*)&pe_s[(ct * 16 + li) * 72 + kk + g * 8];
          ra[ct] = __builtin_amdgcn_mfma_f32_16x16x32_bf16(aq, bp, ra[ct], 0, 0, 0);
        }
      }
#pragma unroll
      for (int ct = 0; ct < 8; ++ct)
#pragma unroll
        for (int r4 = 0; r4 < 4; ++r4)
          R_s[(w * 16 + g * 4 + r4) * 132 + ct * 16 + li] = ra[ct][r4];
      __syncthreads();
#pragma unroll
      for (int ct = 0; ct < 4; ++ct)
#pragma unroll
        for (int r4 = 0; r4 < 4; ++r4) {
          int i = w * 16 + g * 4 + r4;
          int jj = ct * 16 + li;
          int sd = (j0 + jj) - (t0 + i);
          if (sd >= 2) srel[ct][r4] = R_s[i * 132 + (jj - i + 63)];
        }
    }

    // combine, mask, online softmax
    float ptile[4][4];
    float rmax[4] = {-1e30f, -1e30f, -1e30f, -1e30f};
#pragma unroll
    for (int ct = 0; ct < 4; ++ct)
#pragma unroll
      for (int r4 = 0; r4 < 4; ++r4) {
        int i = w * 16 + g * 4 + r4;
        int jj = ct * 16 + li;
        float s = (sc[ct][r4] + srel[ct][r4]) * 0.125f;
        float mk = mask[((size_t)b * 2048 + t0 + i) * 2048 + j0 + jj];
        s = s * mk - 1e10f * (1.f - mk);
        ptile[ct][r4] = s;
        rmax[r4] = fmaxf(rmax[r4], s);
      }
#pragma unroll
    for (int r4 = 0; r4 < 4; ++r4) {
#pragma unroll
      for (int off = 1; off < 16; off <<= 1)
        rmax[r4] = fmaxf(rmax[r4], __shfl_xor(rmax[r4], off));
    }
    float scl[4], rsum[4];
#pragma unroll
    for (int r4 = 0; r4 < 4; ++r4) {
      float mnew = fmaxf(mrun[r4], rmax[r4]);
      scl[r4] = __expf(mrun[r4] - mnew);
      mrun[r4] = mnew;
      rsum[r4] = 0.f;
    }
#pragma unroll
    for (int ct = 0; ct < 4; ++ct)
#pragma unroll
      for (int r4 = 0; r4 < 4; ++r4) {
        float p = __expf(ptile[ct][r4] - mrun[r4]);
        ptile[ct][r4] = p;
        rsum[r4] += p;
      }
#pragma unroll
    for (int r4 = 0; r4 < 4; ++r4) {
#pragma unroll
      for (int off = 1; off < 16; off <<= 1)
        rsum[r4] += __shfl_xor(rsum[r4], off);
      lrun[r4] = lrun[r4] * scl[r4] + rsum[r4];
    }
#pragma unroll
    for (int ct = 0; ct < 4; ++ct)
#pragma unroll
      for (int r4 = 0; r4 < 4; ++r4) oacc[ct][r4] *= scl[r4];

    // write P, then PV
#pragma unroll
    for (int ct = 0; ct < 4; ++ct)
#pragma unroll
      for (int r4 = 0; r4 < 4; ++r4)
        p_s[(w * 16 + g * 4 + r4) * 72 + ct * 16 + li] = (bf16_t)ptile[ct][r4];
    __syncthreads();
#pragma unroll
    for (int kk = 0; kk < 64; kk += 32) {
      bf16x8 ap = *(const bf16x8*)&p_s[(w * 16 + li) * 72 + kk + g * 8];
#pragma unroll
      for (int ct = 0; ct < 4; ++ct) {
        bf16x8 bv = *(const bf16x8*)&vt_s[(ct * 16 + li) * 72 + kk + g * 8];
        oacc[ct] = __builtin_amdgcn_mfma_f32_16x16x32_bf16(ap, bv, oacc[ct], 0, 0, 0);
      }
    }
  }

  // normalize + write
#pragma unroll
  for (int ct = 0; ct < 4; ++ct)
#pragma unroll
    for (int r4 = 0; r4 < 4; ++r4) {
      int i = w * 16 + g * 4 + r4;
      float o = oacc[ct][r4] / lrun[r4];
      attnb[base_bh + (size_t)(t0 + i) * 1024 + ct * 16 + li] = (bf16_t)o;
    }
}

// ---------------- launcher ----------------
extern "C" void kernel_launch(void* const* d_in, const int* in_sizes, int n_in,
                              void* d_out, int out_size, void* d_ws, size_t ws_size,
                              hipStream_t stream) {
  (void)in_sizes; (void)n_in; (void)out_size; (void)ws_size;
  const float* x    = (const float*)d_in[0];
  const float* y    = (const float*)d_in[1];
  const float* mask = (const float*)d_in[2];
  const float* Wq   = (const float*)d_in[3];
  const float* bq   = (const float*)d_in[4];
  const float* Wk   = (const float*)d_in[5];
  const float* bk   = (const float*)d_in[6];
  const float* Wv   = (const float*)d_in[7];
  const float* bv   = (const float*)d_in[8];
  const float* Wp   = (const float*)d_in[9];
  const float* bp   = (const float*)d_in[10];
  const float* rwb  = (const float*)d_in[11];
  const float* rrb  = (const float*)d_in[12];
  const float* Wo   = (const float*)d_in[13];
  const float* bo   = (const float*)d_in[14];
  float* out = (float*)d_out;

  char* ws = (char*)d_ws;
  bf16_t* xb   = (bf16_t*)(ws + 0);            // 8 MB (reused as attnb later)
  bf16_t* yb   = (bf16_t*)(ws + (8ll << 20));
  bf16_t* Wqt  = (bf16_t*)(ws + (16ll << 20));
  bf16_t* Wkt  = (bf16_t*)(ws + (18ll << 20));
  bf16_t* Wvt  = (bf16_t*)(ws + (20ll << 20));
  bf16_t* Wpt  = (bf16_t*)(ws + (22ll << 20));
  bf16_t* Wot  = (bf16_t*)(ws + (24ll << 20));
  bf16_t* sint = (bf16_t*)(ws + (26ll << 20)); // 4 MB
  bf16_t* qwb  = (bf16_t*)(ws + (30ll << 20)); // 8 MB
  bf16_t* qrb  = (bf16_t*)(ws + (38ll << 20));
  bf16_t* kbuf = (bf16_t*)(ws + (46ll << 20));
  bf16_t* vbuf = (bf16_t*)(ws + (54ll << 20));
  bf16_t* peb  = (bf16_t*)(ws + (62ll << 20)); // 4 MB
  bf16_t* attnb = xb;                          // alias: x consumed before attn writes

  k_cast_bf16<<<2048, 256, 0, stream>>>(x, xb, 1048576);
  k_cast_bf16<<<2048, 256, 0, stream>>>(y, yb, 1048576);
  dim3 tg(16, 16);
  k_transpose_cast<<<tg, 256, 0, stream>>>(Wq, Wqt);
  k_transpose_cast<<<tg, 256, 0, stream>>>(Wk, Wkt);
  k_transpose_cast<<<tg, 256, 0, stream>>>(Wv, Wvt);
  k_transpose_cast<<<tg, 256, 0, stream>>>(Wp, Wpt);
  k_transpose_cast<<<tg, 256, 0, stream>>>(Wo, Wot);
  k_sinusoid<<<2048, 512, 0, stream>>>(sint);

  dim3 g1(32, 8);  // M=4096
  dim3 g2(16, 8);  // M=2048
  k_gemm<<<g1, 256, 0, stream>>>(xb, Wqt, bq, rwb, qwb, rrb, qrb, nullptr);
  k_gemm<<<g1, 256, 0, stream>>>(yb, Wkt, bk, nullptr, kbuf, nullptr, nullptr, nullptr);
  k_gemm<<<g1, 256, 0, stream>>>(yb, Wvt, bv, nullptr, vbuf, nullptr, nullptr, nullptr);
  k_gemm<<<g2, 256, 0, stream>>>(sint, Wpt, bp, nullptr, peb, nullptr, nullptr, nullptr);

  dim3 ga(32, 16, 2);
  k_attn<<<ga, 256, 0, stream>>>(qwb, qrb, kbuf, vbuf, peb, mask, attnb);

  k_gemm<<<g1, 256, 0, stream>>>(attnb, Wot, bo, nullptr, nullptr, nullptr, nullptr, out);
}

// Round 3
// 614.131 us; speedup vs baseline: 1.0658x; 1.0658x over previous
//
#include <hip/hip_runtime.h>
#include <math.h>

typedef __bf16 bf16_t;
typedef __bf16 bf16x8 __attribute__((ext_vector_type(8)));
typedef __bf16 bf16x4 __attribute__((ext_vector_type(4)));
typedef float  f32x4  __attribute__((ext_vector_type(4)));

#define DEV __device__ __forceinline__

// q pre-scale: 1/sqrt(64) * log2(e), folded into q GEMM epilogue
#define QSCALE 0.18033688011112042f
// 1e10 * log2(e) for the mask penalty (in exp2 domain)
#define MASKF  1.4426950408889634e10f

DEV float fexp2(float x) {
#if __has_builtin(__builtin_amdgcn_exp2f)
  return __builtin_amdgcn_exp2f(x);
#else
  return __expf(x * 0.6931471805599453f);
#endif
}

DEV void gl_lds16(const bf16_t* g, bf16_t* l) {
  __builtin_amdgcn_global_load_lds(
      (const __attribute__((address_space(1))) void*)g,
      (__attribute__((address_space(3))) void*)l, 16, 0, 0);
}

// ---------------- cast f32 -> bf16 (vectorized) ----------------
__global__ void k_cast_bf16(const float* __restrict__ src, bf16_t* __restrict__ dst, int n4) {
  int idx = blockIdx.x * blockDim.x + threadIdx.x;
  int stride = gridDim.x * blockDim.x;
  const float4* s4 = (const float4*)src;
  for (int i = idx; i < n4; i += stride) {
    float4 v = s4[i];
    bf16x4 o;
    o[0] = (bf16_t)v.x; o[1] = (bf16_t)v.y; o[2] = (bf16_t)v.z; o[3] = (bf16_t)v.w;
    *(bf16x4*)(dst + (size_t)i * 4) = o;
  }
}

// ---------------- transpose + cast weight [1024][1024] f32 -> [N][K] bf16 ----------------
__global__ __launch_bounds__(256) void k_transpose_cast(const float* __restrict__ W, bf16_t* __restrict__ Wt) {
  __shared__ float tile[64][65];
  int k0 = blockIdx.x * 64, n0 = blockIdx.y * 64;
  int r = threadIdx.x >> 2;
  int c0 = (threadIdx.x & 3) * 16;
  const float4* src = (const float4*)(W + (size_t)(k0 + r) * 1024 + n0 + c0);
#pragma unroll
  for (int i = 0; i < 4; ++i) {
    float4 v = src[i];
    tile[r][c0 + i * 4 + 0] = v.x;
    tile[r][c0 + i * 4 + 1] = v.y;
    tile[r][c0 + i * 4 + 2] = v.z;
    tile[r][c0 + i * 4 + 3] = v.w;
  }
  __syncthreads();
#pragma unroll
  for (int half = 0; half < 2; ++half) {
    bf16x8 o;
#pragma unroll
    for (int j = 0; j < 8; ++j) o[j] = (bf16_t)tile[c0 + half * 8 + j][r];
    *(bf16x8*)(Wt + (size_t)(n0 + r) * 1024 + k0 + c0 + half * 8) = o;
  }
}

// ---------------- reversed sinusoidal table [2048][1024] bf16 ----------------
__global__ void k_sinusoid(bf16_t* __restrict__ tab) {
  int i = blockIdx.x;   // row
  int d = threadIdx.x;  // 0..511
  float pos = (float)(2047 - i);
  const float coef = (float)(-9.210340371976184 / 511.0);  // -ln(10000)/(n-1)
  float inv = expf((float)d * coef);
  float st = pos * inv;
  tab[(size_t)i * 1024 + d]       = (bf16_t)sinf(st);
  tab[(size_t)i * 1024 + 512 + d] = (bf16_t)cosf(st);
}

// ---------------- GEMM: C[M][1024] = A[M][1024] @ Bt^T, epilogue (acc+bias+eb)*scale ---------
__global__ __launch_bounds__(256) void k_gemm(
    const bf16_t* __restrict__ A, const bf16_t* __restrict__ Bt,
    const float* __restrict__ bias, const float* __restrict__ ebias, float scale,
    bf16_t* __restrict__ outB, float* __restrict__ outF) {
  __shared__ bf16_t As[128 * 64];
  __shared__ bf16_t Bs[128 * 64];
  const int m0 = blockIdx.x * 128, n0 = blockIdx.y * 128;
  const int tid = threadIdx.x;
  const int w = tid >> 6, lane = tid & 63, li = lane & 15, g = lane >> 4;
  const int mb = (w >> 1) * 64, nb = (w & 1) * 64;
  f32x4 acc[4][4] = {};
  for (int kt = 0; kt < 16; ++kt) {
    __syncthreads();
#pragma unroll
    for (int it = 0; it < 4; ++it) {
      int chunk = it * 256 + tid;
      int r = chunk >> 3, kg = chunk & 7;
      gl_lds16(A + (size_t)(m0 + r) * 1024 + kt * 64 + kg * 8, &As[chunk * 8]);
      gl_lds16(Bt + (size_t)(n0 + r) * 1024 + kt * 64 + kg * 8, &Bs[chunk * 8]);
    }
    __syncthreads();
#pragma unroll
    for (int kk = 0; kk < 64; kk += 32) {
      bf16x8 a[4], b[4];
#pragma unroll
      for (int x = 0; x < 4; ++x) {
        a[x] = *(const bf16x8*)&As[(mb + x * 16 + li) * 64 + kk + g * 8];
        b[x] = *(const bf16x8*)&Bs[(nb + x * 16 + li) * 64 + kk + g * 8];
      }
#pragma unroll
      for (int mr = 0; mr < 4; ++mr)
#pragma unroll
        for (int nr = 0; nr < 4; ++nr)
          acc[mr][nr] = __builtin_amdgcn_mfma_f32_16x16x32_bf16(a[mr], b[nr], acc[mr][nr], 0, 0, 0);
    }
  }
#pragma unroll
  for (int mr = 0; mr < 4; ++mr)
#pragma unroll
    for (int nr = 0; nr < 4; ++nr)
#pragma unroll
      for (int r4 = 0; r4 < 4; ++r4) {
        int row = m0 + mb + mr * 16 + g * 4 + r4;
        int col = n0 + nb + nr * 16 + li;
        float v = acc[mr][nr][r4] + bias[col];
        if (ebias) v += ebias[col];
        v *= scale;
        size_t off = (size_t)row * 1024 + col;
        if (outB) outB[off] = (bf16_t)v;
        if (outF) outF[off] = v;
      }
}

// ---------------- fused rel-attention ----------------
// grid (32 tblocks, 16 heads, 2 batch), 256 threads (4 waves), 64 q-rows / WG.
// Q fragments hoisted to registers (incl. qr = qw + (r_r-r_w)*QSCALE trick).
// K,V reg-prefetched 1 tile ahead, single-buffered LDS, 2 barriers/iter.
// rel: per-wave 5-fragment band R (stride 80, writes [0,79] in-bounds),
// wave-private LDS scratch (no barriers). P in its own buffer (no type-punned
// aliasing -> no TBAA reorder hazard).
__global__ __launch_bounds__(256, 3) void k_attn(
    const bf16_t* __restrict__ qw, const bf16_t* __restrict__ kb,
    const bf16_t* __restrict__ vb, const bf16_t* __restrict__ peb,
    const float* __restrict__ rwb, const float* __restrict__ rrb,
    const float* __restrict__ mask, bf16_t* __restrict__ attnb) {
  const int t0 = blockIdx.x * 64;
  const int h = blockIdx.y;
  const int b = blockIdx.z;
  const int tid = threadIdx.x;
  const int w = tid >> 6, lane = tid & 63, li = lane & 15, g = lane >> 4;

  __shared__ __align__(16) bf16_t k_s[64 * 72];
  __shared__ __align__(16) bf16_t vt_s[64 * 72];
  __shared__ __align__(16) float R_all[4][16 * 80];
  __shared__ __align__(16) bf16_t p_all[4][16 * 72];

  float* R_w = &R_all[w][0];
  bf16_t* p_w = &p_all[w][0];

  const size_t base_bh = (size_t)b * 2048 * 1024 + (size_t)h * 64;

  // ---- prefetch K/V tile 0 into registers ----
  bf16x8 kpf[2], vpf[2];
#pragma unroll
  for (int it = 0; it < 2; ++it) {
    int c = it * 256 + tid;
    int r = c >> 3, s = c & 7;
    kpf[it] = *(const bf16x8*)(kb + base_bh + (size_t)r * 1024 + s * 8);
    vpf[it] = *(const bf16x8*)(vb + base_bh + (size_t)r * 1024 + s * 8);
  }

  // ---- hoist Q fragments (content + relA + relB) ----
  bf16x8 aq[2], arA[2], arB[2];
  {
    int rowA = t0 + w * 16 + li;
    int rowB = rowA + 1 < 2048 ? rowA + 1 : 2047;
#pragma unroll
    for (int kkh = 0; kkh < 2; ++kkh) {
      int cof = kkh * 32 + g * 8;
      aq[kkh] = *(const bf16x8*)(qw + base_bh + (size_t)rowA * 1024 + cof);
      bf16x8 qb = *(const bf16x8*)(qw + base_bh + (size_t)rowB * 1024 + cof);
#pragma unroll
      for (int j = 0; j < 8; ++j) {
        float dj = (rrb[h * 64 + cof + j] - rwb[h * 64 + cof + j]) * QSCALE;
        arA[kkh][j] = (bf16_t)((float)aq[kkh][j] + dj);
        arB[kkh][j] = (bf16_t)((float)qb[j] + dj);
      }
    }
  }

  float mrun[4], lrun[4];
  f32x4 oacc[4] = {};
#pragma unroll
  for (int r4 = 0; r4 < 4; ++r4) { mrun[r4] = -1e30f; lrun[r4] = 0.f; }

  for (int jt = 0; jt < 32; ++jt) {
    const int j0 = jt * 64;
    __syncthreads();  // BAR1: everyone done reading k_s/vt_s of prev iter
    // ---- stage K (b128) and V^T (swizzled scalar) from prefetch regs ----
#pragma unroll
    for (int it = 0; it < 2; ++it) {
      int c = it * 256 + tid;
      int r = c >> 3, s = c & 7;
      *(bf16x8*)&k_s[r * 72 + s * 8] = kpf[it];
      int up = ((r >> 3) ^ s);  // unit-XOR swizzle: conflict-free PV reads
#pragma unroll
      for (int dd = 0; dd < 8; ++dd)
        vt_s[(s * 8 + dd) * 72 + up * 8 + (r & 7)] = vpf[it][dd];
    }
    __syncthreads();  // BAR2: tile visible
    // ---- prefetch next tile ----
    if (jt < 31) {
#pragma unroll
      for (int it = 0; it < 2; ++it) {
        int c = it * 256 + tid;
        int r = c >> 3, s = c & 7;
        kpf[it] = *(const bf16x8*)(kb + base_bh + (size_t)(j0 + 64 + r) * 1024 + s * 8);
        vpf[it] = *(const bf16x8*)(vb + base_bh + (size_t)(j0 + 64 + r) * 1024 + s * 8);
      }
    }

    // ---- content scores ----
    f32x4 sc[4] = {};
#pragma unroll
    for (int kkh = 0; kkh < 2; ++kkh)
#pragma unroll
      for (int ct = 0; ct < 4; ++ct) {
        bf16x8 bk = *(const bf16x8*)&k_s[(ct * 16 + li) * 72 + kkh * 32 + g * 8];
        sc[ct] = __builtin_amdgcn_mfma_f32_16x16x32_bf16(aq[kkh], bk, sc[ct], 0, 0, 0);
      }

    // ---- relative scores: two Toeplitz cases, per-wave private R band ----
    const int sdc = j0 - t0 - w * 16;
#pragma unroll
    for (int cs = 0; cs < 2; ++cs) {
      if (cs == 0 ? (j0 > t0) : (j0 < t0)) continue;
      const int c0 = cs == 0 ? (1984 + j0 - t0) : (j0 - t0 - 65);
      f32x4 ra[5] = {};
#pragma unroll
      for (int kkh = 0; kkh < 2; ++kkh) {
        bf16x8 a = cs ? arB[kkh] : arA[kkh];
#pragma unroll
        for (int f = 0; f < 5; ++f) {
          int c = c0 + (3 - w + f) * 16 + li;
          c = c < 0 ? 0 : (c > 2047 ? 2047 : c);
          bf16x8 bp = *(const bf16x8*)(peb + (size_t)c * 1024 + h * 64 + kkh * 32 + g * 8);
          ra[f] = __builtin_amdgcn_mfma_f32_16x16x32_bf16(a, bp, ra[f], 0, 0, 0);
        }
      }
#pragma unroll
      for (int f = 0; f < 5; ++f)
#pragma unroll
        for (int r4 = 0; r4 < 4; ++r4)
          R_w[(g * 4 + r4) * 80 + f * 16 + li] = ra[f][r4];
      // wave-private: same-type LDS write->read, compiler orders via lgkmcnt
#pragma unroll
      for (int ct = 0; ct < 4; ++ct)
#pragma unroll
        for (int r4 = 0; r4 < 4; ++r4) {
          int il = g * 4 + r4;
          int col = ct * 16 + li - il + 15;
          float rv = R_w[il * 80 + col];
          int sd = sdc + ct * 16 + li - il;
          bool pr = cs ? (sd >= 2) : (sd <= 0);
          sc[ct][r4] += pr ? rv : 0.f;
        }
    }

    // ---- mask + online softmax (exp2 domain) ----
    float rmax[4] = {-3e38f, -3e38f, -3e38f, -3e38f};
#pragma unroll
    for (int ct = 0; ct < 4; ++ct)
#pragma unroll
      for (int r4 = 0; r4 < 4; ++r4) {
        float mk = mask[((size_t)b * 2048 + t0 + w * 16 + g * 4 + r4) * 2048 + j0 + ct * 16 + li];
        float s = fmaf(mk - 1.f, MASKF, sc[ct][r4]);
        sc[ct][r4] = s;
        rmax[r4] = fmaxf(rmax[r4], s);
      }
#pragma unroll
    for (int r4 = 0; r4 < 4; ++r4)
#pragma unroll
      for (int off = 1; off < 16; off <<= 1)
        rmax[r4] = fmaxf(rmax[r4], __shfl_xor(rmax[r4], off));
    float scl[4], rsum[4];
#pragma unroll
    for (int r4 = 0; r4 < 4; ++r4) {
      float mnew = fmaxf(mrun[r4], rmax[r4]);
      scl[r4] = fexp2(mrun[r4] - mnew);
      mrun[r4] = mnew;
      rsum[r4] = 0.f;
    }
#pragma unroll
    for (int ct = 0; ct < 4; ++ct)
#pragma unroll
      for (int r4 = 0; r4 < 4; ++r4) {
        float p = fexp2(sc[ct][r4] - mrun[r4]);
        sc[ct][r4] = p;
        rsum[r4] += p;
      }
#pragma unroll
    for (int r4 = 0; r4 < 4; ++r4) {
#pragma unroll
      for (int off = 1; off < 16; off <<= 1)
        rsum[r4] += __shfl_xor(rsum[r4], off);
      lrun[r4] = lrun[r4] * scl[r4] + rsum[r4];
    }
#pragma unroll
    for (int ct = 0; ct < 4; ++ct)
#pragma unroll
      for (int r4 = 0; r4 < 4; ++r4) oacc[ct][r4] *= scl[r4];

    // ---- P -> LDS (wave-private buffer) ----
#pragma unroll
    for (int ct = 0; ct < 4; ++ct)
#pragma unroll
      for (int r4 = 0; r4 < 4; ++r4)
        p_w[(g * 4 + r4) * 72 + ct * 16 + li] = (bf16_t)sc[ct][r4];

    // ---- PV ----
#pragma unroll
    for (int kkh = 0; kkh < 2; ++kkh) {
      bf16x8 ap = *(const bf16x8*)&p_w[li * 72 + kkh * 32 + g * 8];
#pragma unroll
      for (int ct = 0; ct < 4; ++ct) {
        int d = ct * 16 + li;
        int u2 = (kkh * 4 + g) ^ (d >> 3);
        bf16x8 bv = *(const bf16x8*)&vt_s[d * 72 + u2 * 8];
        oacc[ct] = __builtin_amdgcn_mfma_f32_16x16x32_bf16(ap, bv, oacc[ct], 0, 0, 0);
      }
    }
  }

  // ---- normalize + write ----
#pragma unroll
  for (int ct = 0; ct < 4; ++ct)
#pragma unroll
    for (int r4 = 0; r4 < 4; ++r4) {
      int row = t0 + w * 16 + g * 4 + r4;
      float o = oacc[ct][r4] / lrun[r4];
      attnb[base_bh + (size_t)row * 1024 + ct * 16 + li] = (bf16_t)o;
    }
}

// ---------------- launcher ----------------
extern "C" void kernel_launch(void* const* d_in, const int* in_sizes, int n_in,
                              void* d_out, int out_size, void* d_ws, size_t ws_size,
                              hipStream_t stream) {
  (void)in_sizes; (void)n_in; (void)out_size; (void)ws_size;
  const float* x    = (const float*)d_in[0];
  const float* y    = (const float*)d_in[1];
  const float* mask = (const float*)d_in[2];
  const float* Wq   = (const float*)d_in[3];
  const float* bq   = (const float*)d_in[4];
  const float* Wk   = (const float*)d_in[5];
  const float* bk   = (const float*)d_in[6];
  const float* Wv   = (const float*)d_in[7];
  const float* bv   = (const float*)d_in[8];
  const float* Wp   = (const float*)d_in[9];
  const float* bp   = (const float*)d_in[10];
  const float* rwb  = (const float*)d_in[11];
  const float* rrb  = (const float*)d_in[12];
  const float* Wo   = (const float*)d_in[13];
  const float* bo   = (const float*)d_in[14];
  float* out = (float*)d_out;

  char* ws = (char*)d_ws;
  bf16_t* xb   = (bf16_t*)(ws + 0);            // 8 MB (reused as attnb later)
  bf16_t* yb   = (bf16_t*)(ws + (8ll << 20));
  bf16_t* Wqt  = (bf16_t*)(ws + (16ll << 20));
  bf16_t* Wkt  = (bf16_t*)(ws + (18ll << 20));
  bf16_t* Wvt  = (bf16_t*)(ws + (20ll << 20));
  bf16_t* Wpt  = (bf16_t*)(ws + (22ll << 20));
  bf16_t* Wot  = (bf16_t*)(ws + (24ll << 20));
  bf16_t* sint = (bf16_t*)(ws + (26ll << 20)); // 4 MB
  bf16_t* qwb  = (bf16_t*)(ws + (30ll << 20)); // 8 MB (q + r_w_bias, pre-scaled)
  bf16_t* kbuf = (bf16_t*)(ws + (46ll << 20));
  bf16_t* vbuf = (bf16_t*)(ws + (54ll << 20));
  bf16_t* peb  = (bf16_t*)(ws + (62ll << 20)); // 4 MB
  bf16_t* attnb = xb;                          // alias: x consumed before attn writes

  k_cast_bf16<<<2048, 256, 0, stream>>>(x, xb, 1048576);
  k_cast_bf16<<<2048, 256, 0, stream>>>(y, yb, 1048576);
  dim3 tg(16, 16);
  k_transpose_cast<<<tg, 256, 0, stream>>>(Wq, Wqt);
  k_transpose_cast<<<tg, 256, 0, stream>>>(Wk, Wkt);
  k_transpose_cast<<<tg, 256, 0, stream>>>(Wv, Wvt);
  k_transpose_cast<<<tg, 256, 0, stream>>>(Wp, Wpt);
  k_transpose_cast<<<tg, 256, 0, stream>>>(Wo, Wot);
  k_sinusoid<<<2048, 512, 0, stream>>>(sint);

  dim3 g1(32, 8);  // M=4096
  dim3 g2(16, 8);  // M=2048
  k_gemm<<<g1, 256, 0, stream>>>(xb, Wqt, bq, rwb, QSCALE, qwb, nullptr);
  k_gemm<<<g1, 256, 0, stream>>>(yb, Wkt, bk, nullptr, 1.f, kbuf, nullptr);
  k_gemm<<<g1, 256, 0, stream>>>(yb, Wvt, bv, nullptr, 1.f, vbuf, nullptr);
  k_gemm<<<g2, 256, 0, stream>>>(sint, Wpt, bp, nullptr, 1.f, peb, nullptr);

  dim3 ga(32, 16, 2);
  k_attn<<<ga, 256, 0, stream>>>(qwb, kbuf, vbuf, peb, rwb, rrb, mask, attnb);

  k_gemm<<<g1, 256, 0, stream>>>(attnb, Wot, bo, nullptr, 1.f, nullptr, out);
}